// Round 1
// baseline (160.381 us; speedup 1.0000x reference)
//
#include <hip/hip_runtime.h>

typedef _Float16 half8_t __attribute__((ext_vector_type(8)));
typedef _Float16 half4_t __attribute__((ext_vector_type(4)));
typedef _Float16 half2_t __attribute__((ext_vector_type(2)));
typedef float f32x4 __attribute__((ext_vector_type(4)));

static constexpr int SEQ = 2048;
static constexpr int DEMB = 1024;

__device__ __forceinline__ float fexp2(float x) {
#if __has_builtin(__builtin_amdgcn_exp2f)
  return __builtin_amdgcn_exp2f(x);
#else
  return exp2f(x);
#endif
}

// ---------------- kernel 1: W -> Wt fp16 [192][1024] ----------------
__global__ __launch_bounds__(256) void wt_kernel(const float* __restrict__ Wq,
                                                 const float* __restrict__ Wk,
                                                 const float* __restrict__ Wv,
                                                 _Float16* __restrict__ Wt) {
  int i = blockIdx.x * 256 + threadIdx.x;  // [0, 196608)
  int n = i >> 10;
  int k = i & 1023;
  const float* W = (n < 64) ? Wq : ((n < 128) ? Wk : Wv);
  Wt[i] = (_Float16)W[k * 64 + (n & 63)];
}

// ---------------- kernel 2: QKV projection ----------------
// Each wave: 16 rows of x (m = m0..m0+15), all 192 output cols as 12 MFMA n-tiles.
// nt 0..7 (Q,K): swapped orientation D[n][m] -> row-major Qh/Kh stores.
// nt 8..11 (V): normal orientation D[m][n] -> stores V transposed (Vt[b][h][s]).
__global__ __launch_bounds__(256) void proj_kernel(const float* __restrict__ x,
                                                   const _Float16* __restrict__ Wt,
                                                   _Float16* __restrict__ Qh,
                                                   _Float16* __restrict__ Kh,
                                                   _Float16* __restrict__ Vt) {
  const int lane = threadIdx.x & 63;
  const int wv = threadIdx.x >> 6;
  const int g = lane >> 4;   // 0..3
  const int c = lane & 15;   // 0..15
  const int m0 = blockIdx.x * 64 + wv * 16;

  const f32x4 zero = {0.f, 0.f, 0.f, 0.f};
  f32x4 acc[12];
#pragma unroll
  for (int t = 0; t < 12; ++t) acc[t] = zero;

  const float* xrow = x + (size_t)(m0 + c) * DEMB;

#pragma unroll 2
  for (int kc = 0; kc < DEMB; kc += 32) {
    float4 xa = *(const float4*)(xrow + kc + 8 * g);
    float4 xb = *(const float4*)(xrow + kc + 8 * g + 4);
    half8_t xf;
    xf[0] = (_Float16)xa.x; xf[1] = (_Float16)xa.y;
    xf[2] = (_Float16)xa.z; xf[3] = (_Float16)xa.w;
    xf[4] = (_Float16)xb.x; xf[5] = (_Float16)xb.y;
    xf[6] = (_Float16)xb.z; xf[7] = (_Float16)xb.w;
#pragma unroll
    for (int nt = 0; nt < 12; ++nt) {
      half8_t wf = *(const half8_t*)(Wt + (nt * 16 + c) * 1024 + kc + 8 * g);
      if (nt < 8)
        acc[nt] = __builtin_amdgcn_mfma_f32_16x16x32_f16(wf, xf, acc[nt], 0, 0, 0);
      else
        acc[nt] = __builtin_amdgcn_mfma_f32_16x16x32_f16(xf, wf, acc[nt], 0, 0, 0);
    }
  }

  const int mrow = m0 + c;
#pragma unroll
  for (int nt = 0; nt < 4; ++nt) {  // Q: D[n=4g+r][m=c]
    half4_t h;
    h[0] = (_Float16)acc[nt][0]; h[1] = (_Float16)acc[nt][1];
    h[2] = (_Float16)acc[nt][2]; h[3] = (_Float16)acc[nt][3];
    *(half4_t*)(Qh + mrow * 64 + nt * 16 + 4 * g) = h;
  }
#pragma unroll
  for (int nt = 4; nt < 8; ++nt) {  // K
    half4_t h;
    h[0] = (_Float16)acc[nt][0]; h[1] = (_Float16)acc[nt][1];
    h[2] = (_Float16)acc[nt][2]; h[3] = (_Float16)acc[nt][3];
    *(half4_t*)(Kh + mrow * 64 + (nt - 4) * 16 + 4 * g) = h;
  }
  const int b = m0 >> 11;
  const int sbase = (m0 & 2047) + 4 * g;
#pragma unroll
  for (int nt = 8; nt < 12; ++nt) {  // V: D[m=4g+r][h=c] -> Vt[b][h][s]
    int hh = (nt - 8) * 16 + c;
    half4_t h;
    h[0] = (_Float16)acc[nt][0]; h[1] = (_Float16)acc[nt][1];
    h[2] = (_Float16)acc[nt][2]; h[3] = (_Float16)acc[nt][3];
    *(half4_t*)(Vt + (b * 64 + hh) * 2048 + sbase) = h;
  }
}

// ---------------- kernel 3: causal flash attention ----------------
// 1 wave = 16 q-rows. Swapped QK^T: S^T[k=4g+r (+16kt)][q=c] so each lane holds
// scores of ONE q-row (q=q0+c): scalar running max/sum, row-reduce via shfl_xor 16/32.
// P relayout via wave-private swizzled LDS (row stride 160B, XOR bits 4-6 by (row&7)).
// PV: O^T[h=4g+r][q=c] accumulators -> contiguous float4 stores.
__global__ __launch_bounds__(256) void attn_kernel(const _Float16* __restrict__ Qh,
                                                   const _Float16* __restrict__ Kh,
                                                   const _Float16* __restrict__ Vt,
                                                   float* __restrict__ out) {
  __shared__ __align__(16) char plds_raw[4 * 16 * 160];
  const int lane = threadIdx.x & 63;
  const int wv = threadIdx.x >> 6;
  const int g = lane >> 4;
  const int c = lane & 15;
  const int b = blockIdx.x >> 5;
  const int ii = blockIdx.x & 31;
  // balanced pairing: block total work is uniform across the grid
  int qt;
  if (wv == 0)      qt = 2 * ii;
  else if (wv == 1) qt = 2 * ii + 1;
  else if (wv == 2) qt = 126 - 2 * ii;
  else              qt = 127 - 2 * ii;
  const int q0 = qt * 16;

  char* prow = plds_raw + wv * (16 * 160) + c * 160;
  const unsigned swz = (unsigned)((c & 7) << 4);

  const _Float16* Qrow = Qh + (size_t)(b * 2048 + q0 + c) * 64;
  half8_t qf0 = *(const half8_t*)(Qrow + 8 * g);
  half8_t qf1 = *(const half8_t*)(Qrow + 32 + 8 * g);

  const _Float16* Kb = Kh + (size_t)b * 2048 * 64;
  const _Float16* Vb = Vt + (size_t)b * 64 * 2048;

  const f32x4 zero = {0.f, 0.f, 0.f, 0.f};
  f32x4 acc[4];
#pragma unroll
  for (int t = 0; t < 4; ++t) acc[t] = zero;
  float m2 = -3.0e38f, lsum = 0.f;
  const float CS = 0.18033688011112042f;  // 0.125 * log2(e)
  const int q_lane = q0 + c;
  const int nb = ((q0 + 15) >> 6) + 1;

  for (int jb = 0; jb < nb; ++jb) {
    const int k0 = jb * 64;
    // ---- QK^T: S^T = K * Q^T over h=64 (2 chunks of 32) ----
    f32x4 sacc[4];
#pragma unroll
    for (int kt = 0; kt < 4; ++kt) {
      const _Float16* Krow = Kb + (size_t)(k0 + kt * 16 + c) * 64;
      half8_t kf0 = *(const half8_t*)(Krow + 8 * g);
      half8_t kf1 = *(const half8_t*)(Krow + 32 + 8 * g);
      f32x4 t = zero;
      t = __builtin_amdgcn_mfma_f32_16x16x32_f16(kf0, qf0, t, 0, 0, 0);
      t = __builtin_amdgcn_mfma_f32_16x16x32_f16(kf1, qf1, t, 0, 0, 0);
      sacc[kt] = t;
    }
    // ---- online softmax (base-2 logits) ----
    const bool full = (k0 + 63 <= q0);
    float pv[16];
    float bmax = -3.0e38f;
#pragma unroll
    for (int kt = 0; kt < 4; ++kt) {
#pragma unroll
      for (int r = 0; r < 4; ++r) {
        float sv = sacc[kt][r] * CS;
        if (!full) {
          int kidx = k0 + kt * 16 + 4 * g + r;
          sv = (kidx > q_lane) ? -3.0e38f : sv;
        }
        pv[kt * 4 + r] = sv;
        bmax = fmaxf(bmax, sv);
      }
    }
    bmax = fmaxf(bmax, __shfl_xor(bmax, 16));
    bmax = fmaxf(bmax, __shfl_xor(bmax, 32));
    const float mnew = fmaxf(m2, bmax);
    const float fsc = fexp2(m2 - mnew);
    m2 = mnew;
    float psum = 0.f;
#pragma unroll
    for (int t = 0; t < 16; ++t) {
      pv[t] = fexp2(pv[t] - m2);
      psum += pv[t];
    }
    lsum = lsum * fsc + psum;
#pragma unroll
    for (int ht = 0; ht < 4; ++ht) {
#pragma unroll
      for (int r = 0; r < 4; ++r) acc[ht][r] *= fsc;
    }
    // ---- P -> LDS (row q=c, cols kt*16+4g+2r2..+1), swizzled ----
#pragma unroll
    for (int kt = 0; kt < 4; ++kt) {
#pragma unroll
      for (int r2 = 0; r2 < 2; ++r2) {
        half2_t hv;
        hv[0] = (_Float16)pv[kt * 4 + 2 * r2];
        hv[1] = (_Float16)pv[kt * 4 + 2 * r2 + 1];
        *(half2_t*)(prow + (((unsigned)(kt * 32 + 8 * g + 4 * r2)) ^ swz)) = hv;
      }
    }
    asm volatile("s_waitcnt lgkmcnt(0)" ::: "memory");
    __builtin_amdgcn_sched_barrier(0);
    // ---- P fragments (B-operand): P[q=c][8g+j (+32)] ----
    half8_t pf0 = *(const half8_t*)(prow + (((unsigned)(16 * g)) ^ swz));
    half8_t pf1 = *(const half8_t*)(prow + (((unsigned)(64 + 16 * g)) ^ swz));
    // ---- PV: O^T += V^T * P^T ----
#pragma unroll
    for (int ht = 0; ht < 4; ++ht) {
      const _Float16* Vrow = Vb + (size_t)(16 * ht + c) * 2048 + k0;
      half8_t vf0 = *(const half8_t*)(Vrow + 8 * g);
      half8_t vf1 = *(const half8_t*)(Vrow + 32 + 8 * g);
      acc[ht] = __builtin_amdgcn_mfma_f32_16x16x32_f16(vf0, pf0, acc[ht], 0, 0, 0);
      acc[ht] = __builtin_amdgcn_mfma_f32_16x16x32_f16(vf1, pf1, acc[ht], 0, 0, 0);
    }
  }
  // ---- epilogue: normalize and store ----
  float tot = lsum;
  tot += __shfl_xor(tot, 16);
  tot += __shfl_xor(tot, 32);
  const float inv = 1.0f / tot;
  float* orow = out + (size_t)(b * 2048 + q0 + c) * 64;
#pragma unroll
  for (int ht = 0; ht < 4; ++ht) {
    f32x4 o;
    o[0] = acc[ht][0] * inv; o[1] = acc[ht][1] * inv;
    o[2] = acc[ht][2] * inv; o[3] = acc[ht][3] * inv;
    *(f32x4*)(orow + ht * 16 + 4 * g) = o;
  }
}

extern "C" void kernel_launch(void* const* d_in, const int* in_sizes, int n_in,
                              void* d_out, int out_size, void* d_ws, size_t ws_size,
                              hipStream_t stream) {
  const float* x  = (const float*)d_in[0];
  const float* Wq = (const float*)d_in[1];
  const float* Wk = (const float*)d_in[2];
  const float* Wv = (const float*)d_in[3];
  char* ws = (char*)d_ws;
  _Float16* Wt = (_Float16*)(ws);                // 192*1024*2      = 393216 B
  _Float16* Qh = (_Float16*)(ws + 393216);       // 16384*64*2      = 2097152 B
  _Float16* Kh = (_Float16*)(ws + 2490368);      // 16384*64*2
  _Float16* Vt = (_Float16*)(ws + 4587520);      // 8*64*2048*2
  float* out = (float*)d_out;

  wt_kernel<<<dim3(768), dim3(256), 0, stream>>>(Wq, Wk, Wv, Wt);
  proj_kernel<<<dim3(256), dim3(256), 0, stream>>>(x, Wt, Qh, Kh, Vt);
  attn_kernel<<<dim3(256), dim3(256), 0, stream>>>(Qh, Kh, Vt, out);
}

// Round 2
// 129.737 us; speedup vs baseline: 1.2362x; 1.2362x over previous
//
#include <hip/hip_runtime.h>

typedef _Float16 half8_t __attribute__((ext_vector_type(8)));
typedef _Float16 half4_t __attribute__((ext_vector_type(4)));
typedef _Float16 half2_t __attribute__((ext_vector_type(2)));
typedef float f32x4 __attribute__((ext_vector_type(4)));

static constexpr int SEQ = 2048;
static constexpr int DEMB = 1024;

__device__ __forceinline__ float fexp2(float x) {
#if __has_builtin(__builtin_amdgcn_exp2f)
  return __builtin_amdgcn_exp2f(x);
#else
  return exp2f(x);
#endif
}

// ---------------- kernel 1: W -> Wt fp16 [192][1024] ----------------
__global__ __launch_bounds__(256) void wt_kernel(const float* __restrict__ Wq,
                                                 const float* __restrict__ Wk,
                                                 const float* __restrict__ Wv,
                                                 _Float16* __restrict__ Wt) {
  int i = blockIdx.x * 256 + threadIdx.x;  // [0, 196608)
  int n = i >> 10;
  int k = i & 1023;
  const float* W = (n < 64) ? Wq : ((n < 128) ? Wk : Wv);
  Wt[i] = (_Float16)W[k * 64 + (n & 63)];
}

// ---------------- kernel 2: QKV projection ----------------
// Block = 192 threads = 3 waves sharing 16 x-rows; wave 0->Q, 1->K, 2->V.
// 1024 blocks => 12 waves/CU (vs 4 before). x read once (64 MB HBM floor).
__global__ __launch_bounds__(192) void proj_kernel(const float* __restrict__ x,
                                                   const _Float16* __restrict__ Wt,
                                                   _Float16* __restrict__ Qh,
                                                   _Float16* __restrict__ Kh,
                                                   _Float16* __restrict__ Vt) {
  const int lane = threadIdx.x & 63;
  const int wv = threadIdx.x >> 6;  // 0=Q, 1=K, 2=V
  const int g = lane >> 4;   // 0..3
  const int c = lane & 15;   // 0..15
  const int m0 = blockIdx.x * 16;

  const f32x4 zero = {0.f, 0.f, 0.f, 0.f};
  f32x4 acc[4];
#pragma unroll
  for (int t = 0; t < 4; ++t) acc[t] = zero;

  const float* xrow = x + (size_t)(m0 + c) * DEMB;
  const _Float16* Wbase = Wt + (size_t)(wv * 64 + c) * 1024;
  const bool isV = (wv == 2);

#pragma unroll 2
  for (int kc = 0; kc < DEMB; kc += 32) {
    float4 xa = *(const float4*)(xrow + kc + 8 * g);
    float4 xb = *(const float4*)(xrow + kc + 8 * g + 4);
    half8_t xf;
    xf[0] = (_Float16)xa.x; xf[1] = (_Float16)xa.y;
    xf[2] = (_Float16)xa.z; xf[3] = (_Float16)xa.w;
    xf[4] = (_Float16)xb.x; xf[5] = (_Float16)xb.y;
    xf[6] = (_Float16)xb.z; xf[7] = (_Float16)xb.w;
#pragma unroll
    for (int nt = 0; nt < 4; ++nt) {
      half8_t wf = *(const half8_t*)(Wbase + nt * 16 * 1024 + kc + 8 * g);
      if (!isV)
        acc[nt] = __builtin_amdgcn_mfma_f32_16x16x32_f16(wf, xf, acc[nt], 0, 0, 0);
      else
        acc[nt] = __builtin_amdgcn_mfma_f32_16x16x32_f16(xf, wf, acc[nt], 0, 0, 0);
    }
  }

  const int mrow = m0 + c;
  if (wv == 0) {
#pragma unroll
    for (int nt = 0; nt < 4; ++nt) {
      half4_t h;
      h[0] = (_Float16)acc[nt][0]; h[1] = (_Float16)acc[nt][1];
      h[2] = (_Float16)acc[nt][2]; h[3] = (_Float16)acc[nt][3];
      *(half4_t*)(Qh + mrow * 64 + nt * 16 + 4 * g) = h;
    }
  } else if (wv == 1) {
#pragma unroll
    for (int nt = 0; nt < 4; ++nt) {
      half4_t h;
      h[0] = (_Float16)acc[nt][0]; h[1] = (_Float16)acc[nt][1];
      h[2] = (_Float16)acc[nt][2]; h[3] = (_Float16)acc[nt][3];
      *(half4_t*)(Kh + mrow * 64 + nt * 16 + 4 * g) = h;
    }
  } else {
    const int b = m0 >> 11;
    const int sbase = (m0 & 2047) + 4 * g;
#pragma unroll
    for (int nt = 0; nt < 4; ++nt) {  // V: D[s=4g+r][h=c] -> Vt[b][h][s]
      int hh = nt * 16 + c;
      half4_t h;
      h[0] = (_Float16)acc[nt][0]; h[1] = (_Float16)acc[nt][1];
      h[2] = (_Float16)acc[nt][2]; h[3] = (_Float16)acc[nt][3];
      *(half4_t*)(Vt + (b * 64 + hh) * 2048 + sbase) = h;
    }
  }
}

// ---------------- kernel 3: causal flash attention, 4-way k-split ----------------
// Block = one (b, q-tile of 16 rows). Wave wv handles k-blocks jb = wv, wv+4, ...
// Each wave keeps a partial flash state (m, l, O^T); in-block LDS combine at end.
// 1024 blocks * 4 waves = 16 waves/CU.
__global__ __launch_bounds__(256) void attn_kernel(const _Float16* __restrict__ Qh,
                                                   const _Float16* __restrict__ Kh,
                                                   const _Float16* __restrict__ Vt,
                                                   float* __restrict__ out) {
  __shared__ __align__(16) char plds_raw[4 * 16 * 160];
  __shared__ __align__(16) float Om[4][16][68];  // padded: stride 68 avoids bank clash
  __shared__ float Mm[4][16];
  __shared__ float Ll[4][16];

  const int lane = threadIdx.x & 63;
  const int wv = threadIdx.x >> 6;
  const int g = lane >> 4;
  const int c = lane & 15;
  const int ii = blockIdx.x & 127;
  const int b = blockIdx.x >> 7;
  // interleave big/small q-tiles across consecutive blocks for tail balance
  const int qt = (ii & 1) ? (127 - (ii >> 1)) : (ii >> 1);
  const int q0 = qt * 16;

  char* prow = plds_raw + wv * (16 * 160) + c * 160;
  const unsigned swz = (unsigned)((c & 7) << 4);

  const _Float16* Qrow = Qh + (size_t)(b * 2048 + q0 + c) * 64;
  half8_t qf0 = *(const half8_t*)(Qrow + 8 * g);
  half8_t qf1 = *(const half8_t*)(Qrow + 32 + 8 * g);

  const _Float16* Kb = Kh + (size_t)b * 2048 * 64;
  const _Float16* Vb = Vt + (size_t)b * 64 * 2048;

  const f32x4 zero = {0.f, 0.f, 0.f, 0.f};
  f32x4 acc[4];
#pragma unroll
  for (int t = 0; t < 4; ++t) acc[t] = zero;
  float m2 = -3.0e38f, lsum = 0.f;
  const float CS = 0.18033688011112042f;  // 0.125 * log2(e)
  const int q_lane = q0 + c;
  const int nb = ((q0 + 15) >> 6) + 1;

  for (int jb = wv; jb < nb; jb += 4) {
    const int k0 = jb * 64;
    // ---- QK^T: S^T = K * Q^T over h=64 (2 chunks of 32) ----
    f32x4 sacc[4];
#pragma unroll
    for (int kt = 0; kt < 4; ++kt) {
      const _Float16* Krow = Kb + (size_t)(k0 + kt * 16 + c) * 64;
      half8_t kf0 = *(const half8_t*)(Krow + 8 * g);
      half8_t kf1 = *(const half8_t*)(Krow + 32 + 8 * g);
      f32x4 t = zero;
      t = __builtin_amdgcn_mfma_f32_16x16x32_f16(kf0, qf0, t, 0, 0, 0);
      t = __builtin_amdgcn_mfma_f32_16x16x32_f16(kf1, qf1, t, 0, 0, 0);
      sacc[kt] = t;
    }
    // ---- hoist V fragment loads so L2 latency overlaps softmax VALU ----
    half8_t vf0[4], vf1[4];
#pragma unroll
    for (int ht = 0; ht < 4; ++ht) {
      const _Float16* Vrow = Vb + (size_t)(16 * ht + c) * 2048 + k0;
      vf0[ht] = *(const half8_t*)(Vrow + 8 * g);
      vf1[ht] = *(const half8_t*)(Vrow + 32 + 8 * g);
    }
    // ---- online softmax (base-2 logits) ----
    const bool full = (k0 + 63 <= q0);
    float pv[16];
    float bmax = -3.0e38f;
#pragma unroll
    for (int kt = 0; kt < 4; ++kt) {
#pragma unroll
      for (int r = 0; r < 4; ++r) {
        float sv = sacc[kt][r] * CS;
        if (!full) {
          int kidx = k0 + kt * 16 + 4 * g + r;
          sv = (kidx > q_lane) ? -3.0e38f : sv;
        }
        pv[kt * 4 + r] = sv;
        bmax = fmaxf(bmax, sv);
      }
    }
    bmax = fmaxf(bmax, __shfl_xor(bmax, 16));
    bmax = fmaxf(bmax, __shfl_xor(bmax, 32));
    const float mnew = fmaxf(m2, bmax);
    const float fsc = fexp2(m2 - mnew);
    m2 = mnew;
    float psum = 0.f;
#pragma unroll
    for (int t = 0; t < 16; ++t) {
      pv[t] = fexp2(pv[t] - m2);
      psum += pv[t];
    }
    lsum = lsum * fsc + psum;
#pragma unroll
    for (int ht = 0; ht < 4; ++ht) {
#pragma unroll
      for (int r = 0; r < 4; ++r) acc[ht][r] *= fsc;
    }
    // ---- P -> LDS (row q=c, cols kt*16+4g+2r2..+1), swizzled ----
#pragma unroll
    for (int kt = 0; kt < 4; ++kt) {
#pragma unroll
      for (int r2 = 0; r2 < 2; ++r2) {
        half2_t hv;
        hv[0] = (_Float16)pv[kt * 4 + 2 * r2];
        hv[1] = (_Float16)pv[kt * 4 + 2 * r2 + 1];
        *(half2_t*)(prow + (((unsigned)(kt * 32 + 8 * g + 4 * r2)) ^ swz)) = hv;
      }
    }
    asm volatile("s_waitcnt lgkmcnt(0)" ::: "memory");
    __builtin_amdgcn_sched_barrier(0);
    // ---- P fragments (B-operand): P[q=c][8g+j (+32)] ----
    half8_t pf0 = *(const half8_t*)(prow + (((unsigned)(16 * g)) ^ swz));
    half8_t pf1 = *(const half8_t*)(prow + (((unsigned)(64 + 16 * g)) ^ swz));
    // ---- PV: O^T += V^T * P^T ----
#pragma unroll
    for (int ht = 0; ht < 4; ++ht) {
      acc[ht] = __builtin_amdgcn_mfma_f32_16x16x32_f16(vf0[ht], pf0, acc[ht], 0, 0, 0);
      acc[ht] = __builtin_amdgcn_mfma_f32_16x16x32_f16(vf1[ht], pf1, acc[ht], 0, 0, 0);
    }
  }
  // ---- per-wave partial epilogue: reduce l across g, publish to LDS ----
  lsum += __shfl_xor(lsum, 16);
  lsum += __shfl_xor(lsum, 32);
  Mm[wv][c] = m2;   // same value on all 4 g-lanes of a row
  Ll[wv][c] = lsum;
#pragma unroll
  for (int ht = 0; ht < 4; ++ht) {
    *(f32x4*)&Om[wv][c][ht * 16 + 4 * g] = acc[ht];
  }
  __syncthreads();
  // ---- combine 4 partials: this thread owns row c, cols wv*16 + 4g + 0..3 ----
  float mf = Mm[0][c];
#pragma unroll
  for (int i = 1; i < 4; ++i) mf = fmaxf(mf, Mm[i][c]);
  float sc[4], lf = 0.f;
#pragma unroll
  for (int i = 0; i < 4; ++i) {
    sc[i] = fexp2(Mm[i][c] - mf);
    lf += Ll[i][c] * sc[i];
  }
  const float inv = 1.0f / lf;
  const int col = wv * 16 + 4 * g;
  f32x4 o = zero;
#pragma unroll
  for (int i = 0; i < 4; ++i) {
#pragma unroll
    for (int r = 0; r < 4; ++r) o[r] += Om[i][c][col + r] * sc[i];
  }
#pragma unroll
  for (int r = 0; r < 4; ++r) o[r] *= inv;
  *(f32x4*)(out + (size_t)(b * 2048 + q0 + c) * 64 + col) = o;
}

extern "C" void kernel_launch(void* const* d_in, const int* in_sizes, int n_in,
                              void* d_out, int out_size, void* d_ws, size_t ws_size,
                              hipStream_t stream) {
  const float* x  = (const float*)d_in[0];
  const float* Wq = (const float*)d_in[1];
  const float* Wk = (const float*)d_in[2];
  const float* Wv = (const float*)d_in[3];
  char* ws = (char*)d_ws;
  _Float16* Wt = (_Float16*)(ws);                // 192*1024*2      = 393216 B
  _Float16* Qh = (_Float16*)(ws + 393216);       // 16384*64*2      = 2097152 B
  _Float16* Kh = (_Float16*)(ws + 2490368);      // 16384*64*2
  _Float16* Vt = (_Float16*)(ws + 4587520);      // 8*64*2048*2
  float* out = (float*)d_out;

  wt_kernel<<<dim3(768), dim3(256), 0, stream>>>(Wq, Wk, Wv, Wt);
  proj_kernel<<<dim3(1024), dim3(192), 0, stream>>>(x, Wt, Qh, Kh, Vt);
  attn_kernel<<<dim3(1024), dim3(256), 0, stream>>>(Qh, Kh, Vt, out);
}